// Round 10
// baseline (324.149 us; speedup 1.0000x reference)
//
#include <hip/hip_runtime.h>
#include <hip/hip_fp16.h>

#define NNODES 100000
#define NEDGES 3200000
#define F_IN   256
#define F_HID  32
#define F_OUT  16

#define NB   196      // ceil(100000/512) buckets of 512 nodes
#define NPB  512      // nodes per bucket
#define CAP  20480    // fixed capacity per bucket region (mean 16327, +32 sigma); = 20*1024
#define NCHUNK 256    // phase-A blocks: keeps reservations ~64 records = dense writes
#define CHUNK  12500  // edges per phase-A block
#define RPT_B  20     // phaseB records/thread (CAP/1024)
#define RPT_A  13     // phaseA dst regs/thread (ceil(CHUNK/1024))

#define GRID1B ((NNODES + 255) / 256)  // 391 gemm blocks in the fused kernel (256 rows each)

typedef _Float16 half_t;
typedef half_t half8 __attribute__((ext_vector_type(8)));
typedef float f32x4 __attribute__((ext_vector_type(4)));

// ---------------- CSR build (fixed-capacity buckets) ----------------
// Verified lessons (r1/r3/r4 counters):
//  - scattered 4B HBM writes cost a full 64B line each (r3 k_place: 196MB
//    WRITE for a 12.8MB payload) -> only block-local contiguous reservations
//    write densely (this scheme: ~15MB).
//  - finer reservations (r1: 1024 blocks) fragment lines -> 4x write amp.
//    So NCHUNK stays 256; occupancy comes from 1024 threads/block.
//  - r8 analysis: pipeline is ~6x above its traffic roofline -> serialized
//    latency-bound kernels. This round: grid-fuse phaseA with the (now
//    dinv-free) GEMM so their waves co-reside; dinv scaling moved to k_scale
//    with bit-identical math.

__global__ void k_init(int* __restrict__ bcur) {
    if (threadIdx.x < NB) bcur[threadIdx.x] = threadIdx.x * CAP;
}

// ---------------- FUSED: phaseA (blocks 0..255) || layer-1 GEMM (blocks 256..646) ----
// phaseA: partition edges into bucket regions as packed records (src<<9)|dstLocal;
//   dst chunk register-cached (13 VGPRs) so dst is read exactly once.
// gemm: 16 waves x 16 rows = 256 rows/block; B frags from LDS-transposed W1;
//   A fragments loaded global->register (8 contiguous floats/lane, coalesced);
//   UNSCALED fp32 h written to g1f (dinv applied later in k_scale, bit-identical).
// LDS is a union: phaseA 1.6KB | gemm 50.7KB -> 1 gemm + 1 phaseA block co-reside
// per CU (2048 thr, 52KB), so gemm's BW/MFMA waves hide phaseA's latency stalls.

__global__ __launch_bounds__(1024) void k_fused(
        const int* __restrict__ src, const int* __restrict__ dst,
        int* __restrict__ bcur, unsigned int* __restrict__ rec,
        const float* __restrict__ x, const float* __restrict__ W1,
        float* __restrict__ g1f) {
    __shared__ union {
        struct { int lh[NB]; int lcur[NB]; } pa;
        struct { half_t Wt[32 * 264]; float sbf[16][16 * 33]; } gm;
    } u;
    int t = threadIdx.x;

    if (blockIdx.x < NCHUNK) {
        // ---- phaseA ----
        int e0 = blockIdx.x * CHUNK;
        if (t < NB) u.pa.lh[t] = 0;

        int dcache[RPT_A];
        #pragma unroll
        for (int k = 0; k < RPT_A; ++k) {
            int i = t + k * 1024;
            dcache[k] = (i < CHUNK) ? dst[e0 + i] : -1;
        }
        __syncthreads();
        #pragma unroll
        for (int k = 0; k < RPT_A; ++k)
            if (dcache[k] >= 0) atomicAdd(&u.pa.lh[dcache[k] >> 9], 1);
        __syncthreads();
        if (t < NB) u.pa.lcur[t] = u.pa.lh[t] ? atomicAdd(&bcur[t], u.pa.lh[t]) : 0;
        __syncthreads();
        #pragma unroll
        for (int k = 0; k < RPT_A; ++k) {
            int i = t + k * 1024;
            if (dcache[k] >= 0) {
                int s = src[e0 + i];
                int d = dcache[k];
                int b = d >> 9;
                int pos = atomicAdd(&u.pa.lcur[b], 1);
                rec[pos] = ((unsigned)s << 9) | (unsigned)(d & 511);
            }
        }
    } else {
        // ---- gemm ----
        int gb = blockIdx.x - NCHUNK;
        int wave = t >> 6, lane = t & 63;
        int m = lane & 15, q = lane >> 4;
        int row0 = gb * 256 + wave * 16;

        for (int i = t; i < F_IN * F_HID; i += 1024) {
            int k = i >> 5, f = i & 31;
            u.gm.Wt[f * 264 + k] = (half_t)W1[i];
        }
        __syncthreads();

        half8 B[2][8];
        #pragma unroll
        for (int ft = 0; ft < 2; ++ft)
            #pragma unroll
            for (int kc = 0; kc < 8; ++kc)
                B[ft][kc] = *(const half8*)&u.gm.Wt[(ft * 16 + m) * 264 + kc * 32 + q * 8];

        int grow_a = row0 + m; if (grow_a >= NNODES) grow_a = NNODES - 1;
        const float* rowp = &x[(size_t)grow_a * F_IN + q * 8];

        f32x4 acc0 = {0.f, 0.f, 0.f, 0.f};
        f32x4 acc1 = {0.f, 0.f, 0.f, 0.f};
        #pragma unroll
        for (int kb = 0; kb < 8; ++kb) {      // 8 k-blocks of 32
            const float* sp = rowp + kb * 32;
            float4 xa = *(const float4*)sp;
            float4 xb = *(const float4*)(sp + 4);
            half8 A;
            A[0] = (half_t)xa.x; A[1] = (half_t)xa.y;
            A[2] = (half_t)xa.z; A[3] = (half_t)xa.w;
            A[4] = (half_t)xb.x; A[5] = (half_t)xb.y;
            A[6] = (half_t)xb.z; A[7] = (half_t)xb.w;
            acc0 = __builtin_amdgcn_mfma_f32_16x16x32_f16(A, B[0][kb], acc0, 0, 0, 0);
            acc1 = __builtin_amdgcn_mfma_f32_16x16x32_f16(A, B[1][kb], acc1, 0, 0, 0);
        }

        // epilogue: repack via LDS (stride 33) -> coalesced float4 stores (UNSCALED)
        float* sb = u.gm.sbf[wave];
        #pragma unroll
        for (int r = 0; r < 4; ++r) {
            int rl = q * 4 + r;
            sb[rl * 33 + m]      = acc0[r];
            sb[rl * 33 + 16 + m] = acc1[r];
        }
        __syncthreads();
        int rl = (t >> 2) & 15;
        int w2 = t >> 6;
        int c0 = (t & 3) * 8;
        int grow = gb * 256 + w2 * 16 + rl;
        if (grow < NNODES) {
            const float* sp = &u.gm.sbf[w2][rl * 33 + c0];
            float4 o0 = { sp[0], sp[1], sp[2], sp[3] };
            float4 o1 = { sp[4], sp[5], sp[6], sp[7] };
            float4* gp = (float4*)&g1f[(size_t)grow * 32 + c0];
            gp[0] = o0; gp[1] = o1;
        }
    }
}

// Phase B (single-pass): load the bucket's records into registers (20/thread,
// coalesced stream, fully unrolled), then hist -> shuffle scan -> rowptr/cnt/
// dinv -> placement, all from registers. rec is read from memory exactly once.
__global__ __launch_bounds__(1024) void k_phaseB(
        const unsigned int* __restrict__ rec, const int* __restrict__ bcur,
        int* __restrict__ rowptr, int* __restrict__ cnt,
        float* __restrict__ dinv, int* __restrict__ csr) {
    __shared__ int lh[NPB];
    __shared__ int lsc[NPB];
    __shared__ int wsum[16];
    int t = threadIdx.x, b = blockIdx.x;
    int lo = b * CAP;
    int nrec = bcur[b] - lo;
    if (t < NPB) lh[t] = 0;

    unsigned rcache[RPT_B];
    #pragma unroll
    for (int k = 0; k < RPT_B; ++k) {
        int i = t + k * 1024;
        rcache[k] = (i < nrec) ? rec[lo + i] : 0xFFFFFFFFu;  // recs < 2^26: safe sentinel
    }
    __syncthreads();
    #pragma unroll
    for (int k = 0; k < RPT_B; ++k)
        if (rcache[k] != 0xFFFFFFFFu) atomicAdd(&lh[rcache[k] & 511], 1);
    __syncthreads();

    int lane = t & 63, w = t >> 6;
    int my = (t < NPB) ? lh[t] : 0;
    int v = my;
    #pragma unroll
    for (int d = 1; d < 64; d <<= 1) {
        int tmp = __shfl_up(v, d, 64);
        if (lane >= d) v += tmp;
    }
    if (lane == 63) wsum[w] = v;
    __syncthreads();
    if (w == 0) {
        int s = (lane < 16) ? wsum[lane] : 0;
        #pragma unroll
        for (int d = 1; d < 16; d <<= 1) {
            int tmp = __shfl_up(s, d, 64);
            if (lane >= d) s += tmp;
        }
        if (lane < 16) wsum[lane] = s;
    }
    __syncthreads();
    int ex = v + (w > 0 ? wsum[w - 1] : 0) - my;   // exclusive
    int node = b * NPB + t;
    if (t < NPB) {
        lsc[t] = ex;
        if (node < NNODES) {
            rowptr[node] = lo + ex;
            cnt[node] = my;
            dinv[node] = rsqrtf((float)my + 1.0f);
        }
    }
    __syncthreads();
    #pragma unroll
    for (int k = 0; k < RPT_B; ++k)
        if (rcache[k] != 0xFFFFFFFFu) {
            int dl = rcache[k] & 511;
            int p = atomicAdd(&lsc[dl], 1);
            csr[lo + p] = (int)(rcache[k] >> 9);
        }
}

// ---------------- scale: g1 = fp16(dinv * g1f), bit-identical to old epilogue ----

__global__ __launch_bounds__(256) void k_scale(
        const float* __restrict__ g1f, const float* __restrict__ dinv,
        __half2* __restrict__ g1) {
    int gid = blockIdx.x * 256 + threadIdx.x;      // one thread per 4 floats
    if (gid >= NNODES * 8) return;
    int row = gid >> 3;
    float dv = dinv[row];
    float4 v = ((const float4*)g1f)[gid];
    __half2 h0 = __floats2half2_rn(v.x * dv, v.y * dv);
    __half2 h1 = __floats2half2_rn(v.z * dv, v.w * dv);
    __half2* gp = &g1[(size_t)row * 16 + (gid & 7) * 2];
    gp[0] = h0; gp[1] = h1;
}

// ---------------- gather layer 1 (fp16 rows; fused relu + [Wm|Wv]) ----------------
// Gather is latency-bound (6.4MB row table > 4MB per-XCD L2 -> L2-miss/L3-hit
// chains); unroll 8 keeps 8 independent row reads in flight per thread.

__global__ __launch_bounds__(256) void k_gather_l1(
        const int* __restrict__ rowptr, const int* __restrict__ cnt,
        const int* __restrict__ csr,
        const float* __restrict__ dinv, const __half2* __restrict__ g,
        const float* __restrict__ b1, const float* __restrict__ Wm,
        const float* __restrict__ Wv, __half2* __restrict__ g2) {
    __shared__ float Wcat[F_HID * 32];
    __shared__ float hrow[16][F_HID + 2];
    int tx = threadIdx.x;
    for (int idx = tx; idx < F_HID * 32; idx += 256) {
        int k = idx >> 5, j = idx & 31;
        Wcat[idx] = (j < F_OUT) ? Wm[k * F_OUT + j] : Wv[k * F_OUT + (j - F_OUT)];
    }
    int f2 = tx & 15;
    int lr = tx >> 4;
    int node = blockIdx.x * 16 + lr;
    int start = rowptr[node], end = start + cnt[node];
    float2 acc = __half22float2(g[(size_t)node * 16 + f2]);   // self loop
    int j = start;
    for (; j + 8 <= end; j += 8) {
        int s[8];
        #pragma unroll
        for (int u = 0; u < 8; ++u) s[u] = csr[j + u];
        float2 a[8];
        #pragma unroll
        for (int u = 0; u < 8; ++u) a[u] = __half22float2(g[(size_t)s[u] * 16 + f2]);
        float sx = 0.f, sy = 0.f;
        #pragma unroll
        for (int u = 0; u < 8; ++u) { sx += a[u].x; sy += a[u].y; }
        acc.x += sx; acc.y += sy;
    }
    for (; j + 4 <= end; j += 4) {
        int s0 = csr[j], s1 = csr[j + 1], s2 = csr[j + 2], s3 = csr[j + 3];
        float2 a0 = __half22float2(g[(size_t)s0 * 16 + f2]);
        float2 a1 = __half22float2(g[(size_t)s1 * 16 + f2]);
        float2 a2 = __half22float2(g[(size_t)s2 * 16 + f2]);
        float2 a3 = __half22float2(g[(size_t)s3 * 16 + f2]);
        acc.x += (a0.x + a1.x) + (a2.x + a3.x);
        acc.y += (a0.y + a1.y) + (a2.y + a3.y);
    }
    for (; j < end; ++j) {
        float2 a = __half22float2(g[(size_t)csr[j] * 16 + f2]);
        acc.x += a.x; acc.y += a.y;
    }
    float dv = dinv[node];
    float h0 = dv * acc.x + b1[2 * f2];
    float h1 = dv * acc.y + b1[2 * f2 + 1];
    hrow[lr][2 * f2]     = h0 > 0.f ? h0 : 0.f;
    hrow[lr][2 * f2 + 1] = h1 > 0.f ? h1 : 0.f;
    __syncthreads();
    float o0 = 0.f, o1 = 0.f;
    #pragma unroll
    for (int k = 0; k < F_HID; ++k) {
        float hv = hrow[lr][k];
        o0 = fmaf(hv, Wcat[k * 32 + 2 * f2], o0);
        o1 = fmaf(hv, Wcat[k * 32 + 2 * f2 + 1], o1);
    }
    g2[(size_t)node * 16 + f2] = __floats2half2_rn(o0 * dv, o1 * dv);
}

// ---------------- gather layer 2 (fp16 rows; fused bias + mu/sigma split) --------

__global__ __launch_bounds__(256) void k_gather_out(
        const int* __restrict__ rowptr, const int* __restrict__ cnt,
        const int* __restrict__ csr,
        const float* __restrict__ dinv, const __half2* __restrict__ g,
        const float* __restrict__ bm, const float* __restrict__ bv,
        float* __restrict__ out) {
    int tx = threadIdx.x;
    int f2 = tx & 15;
    int node = blockIdx.x * 16 + (tx >> 4);
    int start = rowptr[node], end = start + cnt[node];
    float2 acc = __half22float2(g[(size_t)node * 16 + f2]);   // self loop
    int j = start;
    for (; j + 8 <= end; j += 8) {
        int s[8];
        #pragma unroll
        for (int u = 0; u < 8; ++u) s[u] = csr[j + u];
        float2 a[8];
        #pragma unroll
        for (int u = 0; u < 8; ++u) a[u] = __half22float2(g[(size_t)s[u] * 16 + f2]);
        float sx = 0.f, sy = 0.f;
        #pragma unroll
        for (int u = 0; u < 8; ++u) { sx += a[u].x; sy += a[u].y; }
        acc.x += sx; acc.y += sy;
    }
    for (; j + 4 <= end; j += 4) {
        int s0 = csr[j], s1 = csr[j + 1], s2 = csr[j + 2], s3 = csr[j + 3];
        float2 a0 = __half22float2(g[(size_t)s0 * 16 + f2]);
        float2 a1 = __half22float2(g[(size_t)s1 * 16 + f2]);
        float2 a2 = __half22float2(g[(size_t)s2 * 16 + f2]);
        float2 a3 = __half22float2(g[(size_t)s3 * 16 + f2]);
        acc.x += (a0.x + a1.x) + (a2.x + a3.x);
        acc.y += (a0.y + a1.y) + (a2.y + a3.y);
    }
    for (; j < end; ++j) {
        float2 a = __half22float2(g[(size_t)csr[j] * 16 + f2]);
        acc.x += a.x; acc.y += a.y;
    }
    float dv = dinv[node];
    int f = 2 * f2;
    if (f < F_OUT) {
        float2 o = { dv * acc.x + bm[f], dv * acc.y + bm[f + 1] };
        *(float2*)&out[(size_t)node * F_OUT + f] = o;
    } else {
        float2 o = { dv * acc.x + bv[f - F_OUT], dv * acc.y + bv[f - F_OUT + 1] };
        *(float2*)&out[(size_t)NNODES * F_OUT + (size_t)node * F_OUT + (f - F_OUT)] = o;
    }
}

// ---------------- launch ----------------

extern "C" void kernel_launch(void* const* d_in, const int* in_sizes, int n_in,
                              void* d_out, int out_size, void* d_ws, size_t ws_size,
                              hipStream_t stream) {
    const float* x   = (const float*)d_in[0];
    const int*   ei  = (const int*)  d_in[1];
    const float* W1  = (const float*)d_in[2];
    const float* b1  = (const float*)d_in[3];
    const float* Wm  = (const float*)d_in[4];
    const float* bm  = (const float*)d_in[5];
    const float* Wv  = (const float*)d_in[6];
    const float* bv  = (const float*)d_in[7];
    float* out = (float*)d_out;

    const int* src = ei;
    const int* dst = ei + NEDGES;

    // workspace layout (bytes), ~59 MB:
    char* ws = (char*)d_ws;
    float*        dinv   = (float*)ws;        ws += 100352 * 4;
    int*          bcur   = (int*)ws;          ws += 256 * 4;
    int*          rowptr = (int*)ws;          ws += 100352 * 4;
    int*          cnt    = (int*)ws;          ws += 100352 * 4;
    int*          csr    = (int*)ws;          ws += (size_t)NB * CAP * 4;   // 16.06 MB
    unsigned int* rec    = (unsigned int*)ws; ws += (size_t)NB * CAP * 4;   // 16.06 MB
    float*        g1f    = (float*)ws;        ws += (size_t)100352 * 32 * 4; // 12.85 MB (unscaled fp32 h)
    __half2*      g2     = (__half2*)ws;

    __half2* g1 = (__half2*)rec;   // rec dead after k_phaseB; k_scale runs after

    // CSR build || layer-1 GEMM (grid-fused: phaseA blocks 0..255, gemm 256..646)
    k_init <<<1, 256, 0, stream>>>(bcur);
    k_fused<<<NCHUNK + GRID1B, 1024, 0, stream>>>(src, dst, bcur, rec, x, W1, g1f);
    k_phaseB<<<NB, 1024, 0, stream>>>(rec, bcur, rowptr, cnt, dinv, csr);

    // apply dinv scaling (bit-identical to the old gemm epilogue)
    k_scale<<<(NNODES * 8 + 255) / 256, 256, 0, stream>>>(g1f, dinv, g1);

    // gather 1 + relu + second transform (mu|sigma fused)
    k_gather_l1<<<NNODES / 16, 256, 0, stream>>>(rowptr, cnt, csr, dinv, g1, b1, Wm, Wv, g2);

    // gather 2 + bias + split to out
    k_gather_out<<<NNODES / 16, 256, 0, stream>>>(rowptr, cnt, csr, dinv, g2, bm, bv, out);
}